// Round 9
// baseline (675.289 us; speedup 1.0000x reference)
//
#include <hip/hip_runtime.h>

typedef unsigned short u16;
typedef __attribute__((ext_vector_type(4))) unsigned short u16x4;
typedef __attribute__((ext_vector_type(8))) short bf16x8;
typedef __attribute__((ext_vector_type(4))) float f32x4;
typedef __attribute__((ext_vector_type(16))) float f32x16;

__device__ __forceinline__ float bf2f(u16 u) {
  union { unsigned i; float f; } v; v.i = ((unsigned)u) << 16; return v.f;
}
__device__ __forceinline__ u16 f2bf(float f) {
  union { float f; unsigned i; } v; v.f = f;
  unsigned r = v.i + 0x7fffu + ((v.i >> 16) & 1u);
  return (u16)(r >> 16);
}
__device__ __forceinline__ void gl_lds16(const u16* g, u16* l) {
  __builtin_amdgcn_global_load_lds((const __attribute__((address_space(1))) unsigned*)g,
                                   (__attribute__((address_space(3))) unsigned*)l, 16, 0, 0);
}
__device__ __forceinline__ f32x16 mfma32(bf16x8 a, bf16x8 b, f32x16 c) {
  return __builtin_amdgcn_mfma_f32_32x32x16_bf16(a, b, c, 0, 0, 0);
}

// ---------------- fp32 -> bf16 weight convert, all 5 weights in ONE launch ----------------
__global__ __launch_bounds__(256) void k_cvt5(const float* __restrict__ s0, const float* __restrict__ s1,
                                              const float* __restrict__ s2, const float* __restrict__ s3,
                                              const float* __restrict__ s4,
                                              u16* __restrict__ d0, u16* __restrict__ d1,
                                              u16* __restrict__ d2, u16* __restrict__ d3,
                                              u16* __restrict__ d4) {
  int b = blockIdx.x;
  const float* S; u16* D; int off;
  if (b < 1536)      { S = s0; D = d0; off = b; }
  else if (b < 2048) { S = s1; D = d1; off = b - 1536; }
  else if (b < 4096) { S = s2; D = d2; off = b - 2048; }
  else if (b < 6144) { S = s3; D = d3; off = b - 4096; }
  else               { S = s4; D = d4; off = b - 6144; }
  int i = (off * 256 + threadIdx.x) * 8;
  f32x4 a = *(const f32x4*)(S + i), c = *(const f32x4*)(S + i + 4);
  bf16x8 r;
  r[0] = (short)f2bf(a.x); r[1] = (short)f2bf(a.y); r[2] = (short)f2bf(a.z); r[3] = (short)f2bf(a.w);
  r[4] = (short)f2bf(c.x); r[5] = (short)f2bf(c.y); r[6] = (short)f2bf(c.z); r[7] = (short)f2bf(c.w);
  *(bf16x8*)(D + i) = r;
}

// ---------------- RMSNorm: one block (256 thr) per token, D=1024 ----------------
__global__ __launch_bounds__(256) void k_rmsnorm(const void* __restrict__ X,
                                                 const float* __restrict__ W,
                                                 u16* __restrict__ Y, int x_ext) {
  const int tok = blockIdx.x, t = threadIdx.x;
  float x0, x1, x2, x3;
  if (x_ext) {
    f32x4 xv = ((const f32x4*)X)[tok * 256 + t];
    x0 = xv.x; x1 = xv.y; x2 = xv.z; x3 = xv.w;
  } else {
    u16x4 xv = ((const u16x4*)X)[tok * 256 + t];
    x0 = bf2f(xv.x); x1 = bf2f(xv.y); x2 = bf2f(xv.z); x3 = bf2f(xv.w);
  }
  float ss = x0 * x0 + x1 * x1 + x2 * x2 + x3 * x3;
#pragma unroll
  for (int m = 32; m; m >>= 1) ss += __shfl_xor(ss, m);
  __shared__ float red[4];
  if ((t & 63) == 0) red[t >> 6] = ss;
  __syncthreads();
  float inv = rsqrtf((red[0] + red[1] + red[2] + red[3]) * (1.f / 1024.f) + 1e-5f);
  f32x4 wv = ((const f32x4*)W)[t];
  u16x4 o;
  o.x = f2bf(x0 * inv * wv.x);
  o.y = f2bf(x1 * inv * wv.y);
  o.z = f2bf(x2 * inv * wv.z);
  o.w = f2bf(x3 * inv * wv.w);
  ((u16x4*)(Y + (size_t)tok * 1024))[t] = o;
}

// ---------------- GEMM 128x128, BK=32 double-buffered, 1 barrier/tile ----------------
// Chunk-XOR LDS (R6 zero-conflict layout): row r's chunk q stored at slot q^((r>>1)&3);
// staging lane fetches global chunk (l&3)^((l>>3)&3) of row t>>2 (4 consecutive lanes = one
// 64 B line, permuted within); reads at slot quad^((l16>>1)&3) -> 2-way aliasing (free).
// Pipeline per K-tile: issue next tile's gl_lds into OTHER buffer (its readers drained at
// last iter's lgkmcnt(0)+barrier) | ds_read current | lgkmcnt(0) | MFMA (covers load
// latency) | vmcnt(0) (residual) | s_barrier. __syncthreads would force-drain vmcnt at the
// top -- raw barrier schedule keeps loads in flight under compute.
// EPI: 0 plain; 1 +R (fp32 if r_ext else bf16). OUTF32: C is float* else u16*.
template <int EPI, int OUTF32>
__global__ __launch_bounds__(256, 3) void k_gemm(const u16* __restrict__ A,
                                                 const u16* __restrict__ W,
                                                 const void* R, void* C,
                                                 int M, int N, int K, int r_ext) {
  __shared__ u16 sA[2][4096];
  __shared__ u16 sB[2][4096];
  const int t = threadIdx.x;
  const int wid = t >> 6, lane = t & 63, quad = lane >> 4, l16 = lane & 15;
  const int wm = wid >> 1, wn = wid & 1;
  const size_t m0 = (size_t)blockIdx.y * 128, n0 = (size_t)blockIdx.x * 128;
  f32x4 acc[4][4] = {};
  const int srow = t >> 2, schunk = (t & 3) ^ ((t >> 3) & 3);
  const u16* Ag = A + (m0 + srow) * K + schunk * 8;
  const u16* Wg = W + (n0 + srow) * (size_t)K + schunk * 8;
  const int csw = (quad ^ ((l16 >> 1) & 3)) * 8;
  const int dofs = wid * 512 + lane * 8;
  // prologue: tile 0 -> buf 0
  gl_lds16(Ag, &sA[0][0] + dofs);
  gl_lds16(Ag + (size_t)64 * K, &sA[0][0] + dofs + 2048);
  gl_lds16(Wg, &sB[0][0] + dofs);
  gl_lds16(Wg + (size_t)64 * K, &sB[0][0] + dofs + 2048);
  asm volatile("s_waitcnt vmcnt(0)" ::: "memory");
  __builtin_amdgcn_s_barrier();
  const int ntile = K >> 5;
  for (int kt = 0; kt < ntile; ++kt) {
    const int cur = kt & 1, nxt = cur ^ 1;
    if (kt + 1 < ntile) {
      const int k0 = (kt + 1) << 5;
      gl_lds16(Ag + k0, &sA[nxt][0] + dofs);
      gl_lds16(Ag + (size_t)64 * K + k0, &sA[nxt][0] + dofs + 2048);
      gl_lds16(Wg + k0, &sB[nxt][0] + dofs);
      gl_lds16(Wg + (size_t)64 * K + k0, &sB[nxt][0] + dofs + 2048);
    }
    bf16x8 a[4], b[4];
#pragma unroll
    for (int mt = 0; mt < 4; ++mt)
      a[mt] = *(const bf16x8*)(&sA[cur][0] + (wm * 64 + mt * 16 + l16) * 32 + csw);
#pragma unroll
    for (int nt = 0; nt < 4; ++nt)
      b[nt] = *(const bf16x8*)(&sB[cur][0] + (wn * 64 + nt * 16 + l16) * 32 + csw);
    asm volatile("s_waitcnt lgkmcnt(0)" ::: "memory");
    __builtin_amdgcn_sched_barrier(0);
    __builtin_amdgcn_s_setprio(1);
#pragma unroll
    for (int mt = 0; mt < 4; ++mt)
#pragma unroll
      for (int nt = 0; nt < 4; ++nt)
        acc[mt][nt] = __builtin_amdgcn_mfma_f32_16x16x32_bf16(a[mt], b[nt], acc[mt][nt], 0, 0, 0);
    __builtin_amdgcn_s_setprio(0);
    asm volatile("s_waitcnt vmcnt(0)" ::: "memory");  // next tile fully landed
    __builtin_amdgcn_s_barrier();                     // + all waves' reads of cur done
  }
#pragma unroll
  for (int mt = 0; mt < 4; ++mt) {
#pragma unroll
    for (int nt = 0; nt < 4; ++nt) {
      size_t row = m0 + wm * 64 + mt * 16 + quad * 4;
      size_t col = n0 + wn * 64 + nt * 16 + l16;
#pragma unroll
      for (int r = 0; r < 4; ++r) {
        float v = acc[mt][nt][r];
        size_t idx = (row + r) * N + col;
        if (EPI == 1) v += r_ext ? ((const float*)R)[idx] : bf2f(((const u16*)R)[idx]);
        if (OUTF32) ((float*)C)[idx] = v;
        else ((u16*)C)[idx] = f2bf(v);
      }
    }
  }
}

// ---------------- Fused FFN up-projection, BK=32 double-buffered (48 KiB LDS) ----------------
__global__ __launch_bounds__(256, 2) void k_ffn(const u16* __restrict__ A,
                                                const u16* __restrict__ W1,
                                                const u16* __restrict__ W3,
                                                u16* __restrict__ C,
                                                int M, int N, int K) {
  __shared__ u16 sA[2][4096];
  __shared__ u16 sB1[2][4096];
  __shared__ u16 sB3[2][4096];
  const int t = threadIdx.x;
  const int wid = t >> 6, lane = t & 63, quad = lane >> 4, l16 = lane & 15;
  const int wm = wid >> 1, wn = wid & 1;
  const size_t m0 = (size_t)blockIdx.y * 128, n0 = (size_t)blockIdx.x * 128;
  f32x4 acc1[4][4] = {};
  f32x4 acc3[4][4] = {};
  const int srow = t >> 2, schunk = (t & 3) ^ ((t >> 3) & 3);
  const u16* Ag = A + (m0 + srow) * K + schunk * 8;
  const u16* W1g = W1 + (n0 + srow) * (size_t)K + schunk * 8;
  const u16* W3g = W3 + (n0 + srow) * (size_t)K + schunk * 8;
  const int csw = (quad ^ ((l16 >> 1) & 3)) * 8;
  const int dofs = wid * 512 + lane * 8;
  gl_lds16(Ag, &sA[0][0] + dofs);
  gl_lds16(Ag + (size_t)64 * K, &sA[0][0] + dofs + 2048);
  gl_lds16(W1g, &sB1[0][0] + dofs);
  gl_lds16(W1g + (size_t)64 * K, &sB1[0][0] + dofs + 2048);
  gl_lds16(W3g, &sB3[0][0] + dofs);
  gl_lds16(W3g + (size_t)64 * K, &sB3[0][0] + dofs + 2048);
  asm volatile("s_waitcnt vmcnt(0)" ::: "memory");
  __builtin_amdgcn_s_barrier();
  const int ntile = K >> 5;
  for (int kt = 0; kt < ntile; ++kt) {
    const int cur = kt & 1, nxt = cur ^ 1;
    if (kt + 1 < ntile) {
      const int k0 = (kt + 1) << 5;
      gl_lds16(Ag + k0, &sA[nxt][0] + dofs);
      gl_lds16(Ag + (size_t)64 * K + k0, &sA[nxt][0] + dofs + 2048);
      gl_lds16(W1g + k0, &sB1[nxt][0] + dofs);
      gl_lds16(W1g + (size_t)64 * K + k0, &sB1[nxt][0] + dofs + 2048);
      gl_lds16(W3g + k0, &sB3[nxt][0] + dofs);
      gl_lds16(W3g + (size_t)64 * K + k0, &sB3[nxt][0] + dofs + 2048);
    }
    bf16x8 a[4], b1[4], b3[4];
#pragma unroll
    for (int mt = 0; mt < 4; ++mt)
      a[mt] = *(const bf16x8*)(&sA[cur][0] + (wm * 64 + mt * 16 + l16) * 32 + csw);
#pragma unroll
    for (int nt = 0; nt < 4; ++nt) {
      b1[nt] = *(const bf16x8*)(&sB1[cur][0] + (wn * 64 + nt * 16 + l16) * 32 + csw);
      b3[nt] = *(const bf16x8*)(&sB3[cur][0] + (wn * 64 + nt * 16 + l16) * 32 + csw);
    }
    asm volatile("s_waitcnt lgkmcnt(0)" ::: "memory");
    __builtin_amdgcn_sched_barrier(0);
    __builtin_amdgcn_s_setprio(1);
#pragma unroll
    for (int mt = 0; mt < 4; ++mt)
#pragma unroll
      for (int nt = 0; nt < 4; ++nt) {
        acc1[mt][nt] = __builtin_amdgcn_mfma_f32_16x16x32_bf16(a[mt], b1[nt], acc1[mt][nt], 0, 0, 0);
        acc3[mt][nt] = __builtin_amdgcn_mfma_f32_16x16x32_bf16(a[mt], b3[nt], acc3[mt][nt], 0, 0, 0);
      }
    __builtin_amdgcn_s_setprio(0);
    asm volatile("s_waitcnt vmcnt(0)" ::: "memory");
    __builtin_amdgcn_s_barrier();
  }
#pragma unroll
  for (int mt = 0; mt < 4; ++mt) {
#pragma unroll
    for (int nt = 0; nt < 4; ++nt) {
      size_t row = m0 + wm * 64 + mt * 16 + quad * 4;
      size_t col = n0 + wn * 64 + nt * 16 + l16;
#pragma unroll
      for (int r = 0; r < 4; ++r) {
        float v1 = acc1[mt][nt][r];
        float v3 = acc3[mt][nt][r];
        float h = v1 / (1.f + __expf(-v1)) * v3;
        C[(row + r) * N + col] = f2bf(h);
      }
    }
  }
}

// ---------------- RoPE + repack: qkv(B,S,3,H,64) -> Qr,Kr (bh,S,64), Vt (bh,64,S) ----------------
// Qr PRE-SCALED by SCL = (1/sqrt(64))*log2(e): QK^T emits scores in log2-domain.
#define SCL 0.18033688011112042f

__global__ __launch_bounds__(256) void k_rope(const u16* __restrict__ QKV,
                                              const float* __restrict__ POS,
                                              const float* __restrict__ ASC,
                                              u16* __restrict__ Qr, u16* __restrict__ Kr,
                                              u16* __restrict__ Vt) {
  const int bh = blockIdx.x, b = bh >> 4, h = bh & 15;
  const int s0 = blockIdx.y * 128;
  const int t = threadIdx.x;
  const int pr = t & 31, a = pr >> 3, f = pr & 7, srow = t >> 5;
  const float asc = ASC[a];
  const float invf = exp2f(-(float)f * (13.28771237954945f / 8.f));  // 10000^(-f/8)
  for (int pass = 0; pass < 16; ++pass) {
    int s = s0 + pass * 8 + srow;
    float ang = POS[((size_t)b * 2048 + s) * 4 + a] * asc * invf;
    float sn, cs;
    sincosf(ang, &sn, &cs);
    size_t ib = ((size_t)b * 2048 + s) * 3072 + h * 64 + a * 16 + f * 2;
    size_t ob = ((size_t)bh * 2048 + s) * 64 + a * 16 + f * 2;
    unsigned qw = *(const unsigned*)(QKV + ib);
    float e = bf2f((u16)(qw & 0xffff)), o = bf2f((u16)(qw >> 16));
    *(unsigned*)(Qr + ob) =
        (unsigned)f2bf((e * cs - o * sn) * SCL) | ((unsigned)f2bf((o * cs + e * sn) * SCL) << 16);
    unsigned kw = *(const unsigned*)(QKV + ib + 1024);
    e = bf2f((u16)(kw & 0xffff));
    o = bf2f((u16)(kw >> 16));
    *(unsigned*)(Kr + ob) = (unsigned)f2bf(e * cs - o * sn) | ((unsigned)f2bf(o * cs + e * sn) << 16);
  }
  __shared__ u16 vt[64 * 130];
#pragma unroll
  for (int it = 0; it < 32; ++it) {
    int idx = it * 256 + t, sl = idx >> 6, d = idx & 63;
    vt[d * 130 + sl] = QKV[((size_t)b * 2048 + s0 + sl) * 3072 + 2048 + h * 64 + d];
  }
  __syncthreads();
#pragma unroll
  for (int it = 0; it < 32; ++it) {
    int idx = it * 256 + t, d = idx >> 7, sl = idx & 127;
    Vt[((size_t)bh * 64 + d) * 2048 + s0 + sl] = vt[d * 130 + sl];
  }
}

// ---------------- Flash attention, 32x32 MFMA, shift-free softmax ----------------
__global__ __launch_bounds__(256, 3) void k_attn(const u16* __restrict__ Qr,
                                                 const u16* __restrict__ Kr,
                                                 const u16* __restrict__ Vt,
                                                 u16* __restrict__ O) {
  __shared__ u16 sK[2][4096];
  __shared__ u16 sV[2][4096];
  const int t = threadIdx.x, wid = t >> 6, lane = t & 63;
  const int il = lane & 31, hh = lane >> 5;
  const int bh = blockIdx.x;
  const int q0 = blockIdx.y * 128 + wid * 32;
  const size_t base = (size_t)bh * 2048 * 64;

  bf16x8 qf[4];
#pragma unroll
  for (int c = 0; c < 4; ++c)
    qf[c] = *(const bf16x8*)(Qr + base + (size_t)(q0 + il) * 64 + c * 16 + hh * 8);

  bf16x8 ones;
#pragma unroll
  for (int i = 0; i < 8; ++i) ones[i] = (short)0x3F80;  // bf16 1.0

  const f32x16 ZERO = {};
  f32x16 oa[2] = {ZERO, ZERO};
  f32x16 ol = ZERO;  // running sum-of-P (every element = full column sum)

  const u16* Kb = Kr + base;
  const u16* Vb = Vt + base;
  const int cc = t & 7, r0 = t >> 3;
  {
    bf16x8 k0 = *(const bf16x8*)(Kb + (size_t)r0 * 64 + cc * 8);
    bf16x8 k1 = *(const bf16x8*)(Kb + (size_t)(r0 + 32) * 64 + cc * 8);
    bf16x8 v0 = *(const bf16x8*)(Vb + (size_t)r0 * 2048 + cc * 8);
    bf16x8 v1 = *(const bf16x8*)(Vb + (size_t)(r0 + 32) * 2048 + cc * 8);
    *(bf16x8*)(sK[0] + (cc * 64 + (r0 ^ cc)) * 8) = k0;
    *(bf16x8*)(sK[0] + (cc * 64 + ((r0 + 32) ^ cc)) * 8) = k1;
    *(bf16x8*)(sV[0] + (cc * 64 + (r0 ^ cc)) * 8) = v0;
    *(bf16x8*)(sV[0] + (cc * 64 + ((r0 + 32) ^ cc)) * 8) = v1;
  }
  __syncthreads();

  for (int it = 0; it < 32; ++it) {
    const u16* kb = sK[it & 1];
    const u16* vb = sV[it & 1];
    bf16x8 nk0, nk1, nv0, nv1;
    const int last = (it == 31);
    if (!last) {
      int kv = (it + 1) * 64;
      nk0 = *(const bf16x8*)(Kb + (size_t)(kv + r0) * 64 + cc * 8);
      nk1 = *(const bf16x8*)(Kb + (size_t)(kv + r0 + 32) * 64 + cc * 8);
      nv0 = *(const bf16x8*)(Vb + (size_t)r0 * 2048 + kv + cc * 8);
      nv1 = *(const bf16x8*)(Vb + (size_t)(r0 + 32) * 2048 + kv + cc * 8);
    }
    f32x16 sacc[2];
    __builtin_amdgcn_s_setprio(1);
#pragma unroll
    for (int kt = 0; kt < 2; ++kt) {
#pragma unroll
      for (int c = 0; c < 4; ++c) {
        int ch = c * 2 + hh;
        bf16x8 kf = *(const bf16x8*)(kb + (ch * 64 + ((kt * 32 + il) ^ ch)) * 8);
        sacc[kt] = (c == 0) ? mfma32(kf, qf[0], ZERO) : mfma32(kf, qf[c], sacc[kt]);
      }
    }
    __builtin_amdgcn_s_setprio(0);
    bf16x8 pa[4];
#pragma unroll
    for (int kt = 0; kt < 2; ++kt) {
      float p[16];
#pragma unroll
      for (int r = 0; r < 16; ++r) p[r] = exp2f(sacc[kt][r]);
      unsigned w[8];
#pragma unroll
      for (int i = 0; i < 8; ++i)
        asm("v_cvt_pk_bf16_f32 %0, %1, %2" : "=v"(w[i]) : "v"(p[2 * i]), "v"(p[2 * i + 1]));
      asm("v_permlane32_swap_b32 %0, %1" : "+v"(w[0]), "+v"(w[2]));
      asm("v_permlane32_swap_b32 %0, %1" : "+v"(w[1]), "+v"(w[3]));
      asm("v_permlane32_swap_b32 %0, %1" : "+v"(w[4]), "+v"(w[6]));
      asm("v_permlane32_swap_b32 %0, %1" : "+v"(w[5]), "+v"(w[7]));
      union { unsigned u[4]; bf16x8 v; } f0, f1;
      f0.u[0] = w[0]; f0.u[1] = w[1]; f0.u[2] = w[2]; f0.u[3] = w[3];
      f1.u[0] = w[4]; f1.u[1] = w[5]; f1.u[2] = w[6]; f1.u[3] = w[7];
      pa[kt * 2] = f0.v;
      pa[kt * 2 + 1] = f1.v;
    }
    __builtin_amdgcn_s_setprio(1);
#pragma unroll
    for (int ks = 0; ks < 4; ++ks) {
      int sc = ks * 2 + hh;
      ol = mfma32(ones, pa[ks], ol);  // l-sum on the matrix pipe
#pragma unroll
      for (int dt = 0; dt < 2; ++dt) {
        bf16x8 vf = *(const bf16x8*)(vb + (sc * 64 + ((dt * 32 + il) ^ sc)) * 8);
        oa[dt] = mfma32(vf, pa[ks], oa[dt]);
      }
    }
    __builtin_amdgcn_s_setprio(0);
    if (!last) {
      u16* kn = sK[(it + 1) & 1];
      u16* vn = sV[(it + 1) & 1];
      *(bf16x8*)(kn + (cc * 64 + (r0 ^ cc)) * 8) = nk0;
      *(bf16x8*)(kn + (cc * 64 + ((r0 + 32) ^ cc)) * 8) = nk1;
      *(bf16x8*)(vn + (cc * 64 + (r0 ^ cc)) * 8) = nv0;
      *(bf16x8*)(vn + (cc * 64 + ((r0 + 32) ^ cc)) * 8) = nv1;
    }
    __syncthreads();
  }
  const int b = bh >> 4, hd = bh & 15;
  {
    float inv = 1.f / ol[0];
    int q = q0 + il;
#pragma unroll
    for (int dt = 0; dt < 2; ++dt) {
#pragma unroll
      for (int g = 0; g < 4; ++g) {
        u16x4 pk;
        pk.x = f2bf(oa[dt][4 * g + 0] * inv);
        pk.y = f2bf(oa[dt][4 * g + 1] * inv);
        pk.z = f2bf(oa[dt][4 * g + 2] * inv);
        pk.w = f2bf(oa[dt][4 * g + 3] * inv);
        *(u16x4*)(O + ((size_t)b * 2048 + q) * 1024 + hd * 64 + dt * 32 + 8 * g + 4 * hh) = pk;
      }
    }
  }
}

extern "C" void kernel_launch(void* const* d_in, const int* in_sizes, int n_in,
                              void* d_out, int out_size, void* d_ws, size_t ws_size,
                              hipStream_t stream) {
  const float* src    = (const float*)d_in[0];
  const float* pos    = (const float*)d_in[1];
  const float* w_qkv  = (const float*)d_in[2];
  const float* w_out  = (const float*)d_in[3];
  const float* n1w    = (const float*)d_in[4];
  const float* n2w    = (const float*)d_in[5];
  const float* w1     = (const float*)d_in[6];
  const float* w2     = (const float*)d_in[7];
  const float* w3     = (const float*)d_in[8];
  const float* ascale = (const float*)d_in[9];
  char* ws = (char*)d_ws;
  u16* xn  = (u16*)(ws);                          // [0,16)
  u16* qkv = (u16*)(ws + ((size_t)16 << 20));     // [16,64)
  u16* Qr  = (u16*)(ws);                          // [0,16)   over xn (dead)
  u16* Kr  = (u16*)(ws + ((size_t)64 << 20));     // [64,80)
  u16* Vt  = (u16*)(ws + ((size_t)80 << 20));     // [80,96)
  u16* att = (u16*)(ws + ((size_t)16 << 20));     // [16,32)  over qkv head (dead)
  u16* x   = (u16*)(ws + ((size_t)80 << 20));     // [80,96)  over Vt (dead)
  u16* xn2 = (u16*)(ws);                          // [0,16)   over Qr (dead)
  u16* h1  = (u16*)(ws + ((size_t)16 << 20));     // [16,80)  over att/Kr (dead)
  u16* bqkv = (u16*)(ws + ((size_t)96 << 20));    // [96,102)  6 MB
  u16* bout = (u16*)(ws + ((size_t)102 << 20));   // [102,104) 2 MB
  u16* b1   = (u16*)(ws + ((size_t)104 << 20));   // [104,112) 8 MB
  u16* b3   = (u16*)(ws + ((size_t)112 << 20));   // [112,120) 8 MB
  u16* b2   = (u16*)(ws + ((size_t)120 << 20));   // [120,128) 8 MB

  // Weight conversion fp32 -> bf16, single launch (graph-safe)
  k_cvt5<<<8192, 256, 0, stream>>>(w_qkv, w_out, w1, w3, w2, bqkv, bout, b1, b3, b2);

  k_rmsnorm<<<8192, 256, 0, stream>>>(src, n1w, xn, 1);
  k_gemm<0, 0><<<dim3(24, 64), 256, 0, stream>>>(xn, bqkv, nullptr, qkv, 8192, 3072, 1024, 0);
  k_rope<<<dim3(64, 16), 256, 0, stream>>>(qkv, pos, ascale, Qr, Kr, Vt);
  k_attn<<<dim3(64, 16), 256, 0, stream>>>(Qr, Kr, Vt, att);
  k_gemm<1, 0><<<dim3(8, 64), 256, 0, stream>>>(att, bout, src, x, 8192, 1024, 1024, 1);
  k_rmsnorm<<<8192, 256, 0, stream>>>(x, n2w, xn2, 0);
  k_ffn<<<dim3(32, 64), 256, 0, stream>>>(xn2, b1, b3, h1, 8192, 4096, 1024);
  k_gemm<1, 1><<<dim3(8, 64), 256, 0, stream>>>(h1, b2, x, d_out, 8192, 1024, 4096, 0);
}